// Round 3
// baseline (3167.345 us; speedup 1.0000x reference)
//
#include <hip/hip_runtime.h>
#include <math.h>

#define BB 32
#define TT 128
#define EE 128
#define HD 128
#define G4 512   // 4*H
#define NV 32000

// ---------------- Kernel A: Z0x = emb[inputs] @ W0 + b0 ----------------
__global__ __launch_bounds__(256) void k_embed_w0(
    const int* __restrict__ inputs, const float* __restrict__ emb,
    const float* __restrict__ W0, const float* __restrict__ b0,
    float* __restrict__ Z0x)
{
    __shared__ float xs[8][EE];
    const int r0 = blockIdx.x * 8;
    const int tid = threadIdx.x;
    for (int i = tid; i < 8 * EE; i += 256) {
        int r = i >> 7, e = i & 127;
        int tok = inputs[r0 + r];
        xs[r][e] = emb[tok * EE + e];
    }
    __syncthreads();
    const int c2 = tid * 2;
    float2 bb2 = *(const float2*)&b0[c2];
    float acc[8][2];
    #pragma unroll
    for (int r = 0; r < 8; ++r) { acc[r][0] = bb2.x; acc[r][1] = bb2.y; }
    for (int e = 0; e < EE; ++e) {
        float2 w = *(const float2*)&W0[e * G4 + c2];
        #pragma unroll
        for (int r = 0; r < 8; ++r) {
            float x = xs[r][e];
            acc[r][0] = fmaf(x, w.x, acc[r][0]);
            acc[r][1] = fmaf(x, w.y, acc[r][1]);
        }
    }
    #pragma unroll
    for (int r = 0; r < 8; ++r) {
        float2 o2; o2.x = acc[r][0]; o2.y = acc[r][1];
        *(float2*)&Z0x[(size_t)(r0 + r) * G4 + c2] = o2;
    }
}

// ---------------- Kernel B: distributed 2-layer LSTM recurrence ----------------
// 256 blocks x 256 thr. Group = 8 blocks (same i%8 -> same XCD heuristic),
// one group per batch element. Block owns 16 h-indices (64 gate columns/matrix).
// Weight columns register-resident: wave0=U0, wave1=W1, wave2=U1, wave3=gates.
// Phase p computes a_p (layer0 t=p) and b_{p-1} (layer1 t=p-1): 1 sync/phase.
// h exchange via agent-scope relaxed atomics (coherence independent of fences).
__global__ __launch_bounds__(256, 2) void k_lstm_d(
    const float* __restrict__ Z0x,
    const float* __restrict__ U0, const float* __restrict__ W1,
    const float* __restrict__ U1, const float* __restrict__ b1,
    float* __restrict__ h0buf, float* __restrict__ h1buf,
    float* __restrict__ y, unsigned int* __restrict__ flags)
{
    const int i = blockIdx.x;
    const int r = i & 7;            // xcd (heuristic)
    const int s = i >> 3;           // slot 0..31
    const int q = s >> 3;           // 0..3
    const int k = s & 7;            // member in group
    const int g = r * 4 + q;        // group 0..31 == batch element
    const int b = g;
    const int o = k * 16;           // owned h-index base
    const int tid = threadIdx.x;
    const int wid = tid >> 6;
    const int lane = tid & 63;

    __shared__ float h0cur[HD];
    __shared__ float h1cur[HD];
    __shared__ float z0s[64], zWs[64], zUs[64];

    const int c = lane;                            // column slot 0..63
    const int col = (c >> 4) * HD + o + (c & 15);  // gate*128 + h-index

    // register-resident weight column
    float wreg[128];
    const float* Wm = (wid == 0) ? U0 : (wid == 1) ? W1 : U1;
    if (wid < 3) {
        #pragma unroll
        for (int e = 0; e < 128; ++e) wreg[e] = Wm[e * G4 + col];
    }
    float c0 = 0.f, c1 = 0.f;   // cell state (wave3 lanes)

    unsigned int* myflag = flags + g * 128 + k * 16;   // 64B-spaced flags
    unsigned int* gflags = flags + g * 128;

    for (int p = 0; p <= TT; ++p) {
        if (p > 0) {
            if (tid < 8) {
                while (__hip_atomic_load(gflags + tid * 16, __ATOMIC_ACQUIRE,
                                         __HIP_MEMORY_SCOPE_AGENT) < (unsigned)p) {
                    __builtin_amdgcn_s_sleep(2);
                }
            }
            __syncthreads();
        }
        const int rpar = (p + 1) & 1;   // parity holding h0_{p-1}, h1_{p-2}
        if (tid < 128) {
            h0cur[tid] = __hip_atomic_load(&h0buf[(rpar * BB + b) * HD + tid],
                                           __ATOMIC_RELAXED, __HIP_MEMORY_SCOPE_AGENT);
        } else {
            h1cur[tid - 128] = __hip_atomic_load(&h1buf[(rpar * BB + b) * HD + (tid - 128)],
                                                 __ATOMIC_RELAXED, __HIP_MEMORY_SCOPE_AGENT);
        }
        __syncthreads();

        if (wid < 3) {
            const float* hs = (wid == 2) ? h1cur : h0cur;
            float init = 0.f;
            if (wid == 0) init = (p < TT) ? Z0x[(size_t)(b * TT + p) * G4 + col] : 0.f;
            else if (wid == 1) init = b1[col];
            float a0 = 0.f, a1 = 0.f, a2 = 0.f, a3 = 0.f;
            const float4* h4 = (const float4*)hs;
            #pragma unroll
            for (int e4 = 0; e4 < 32; ++e4) {
                float4 hv = h4[e4];
                a0 = fmaf(wreg[4 * e4 + 0], hv.x, a0);
                a1 = fmaf(wreg[4 * e4 + 1], hv.y, a1);
                a2 = fmaf(wreg[4 * e4 + 2], hv.z, a2);
                a3 = fmaf(wreg[4 * e4 + 3], hv.w, a3);
            }
            float dot = ((a0 + a1) + (a2 + a3)) + init;
            if (wid == 0)      z0s[c] = dot;
            else if (wid == 1) zWs[c] = dot;
            else               zUs[c] = dot;
        }
        __syncthreads();

        if (wid == 3) {
            if (lane < 16 && p < TT) {            // layer0 gates, h-index o+lane
                int j = lane;
                float zi = z0s[j], zf = z0s[16 + j], zc = z0s[32 + j], zo = z0s[48 + j];
                float ig = 1.f / (1.f + expf(-zi));
                float fg = 1.f / (1.f + expf(-zf));
                float og = 1.f / (1.f + expf(-zo));
                c0 = fg * c0 + ig * tanhf(zc);
                float h0n = og * tanhf(c0);
                __hip_atomic_store(&h0buf[((p & 1) * BB + b) * HD + o + j], h0n,
                                   __ATOMIC_RELAXED, __HIP_MEMORY_SCOPE_AGENT);
            } else if (lane >= 16 && lane < 32 && p > 0) {  // layer1 gates, t=p-1
                int j = lane - 16;
                float zi = zWs[j] + zUs[j];
                float zf = zWs[16 + j] + zUs[16 + j];
                float zc = zWs[32 + j] + zUs[32 + j];
                float zo = zWs[48 + j] + zUs[48 + j];
                float ig = 1.f / (1.f + expf(-zi));
                float fg = 1.f / (1.f + expf(-zf));
                float og = 1.f / (1.f + expf(-zo));
                c1 = fg * c1 + ig * tanhf(zc);
                float h1n = og * tanhf(c1);
                __hip_atomic_store(&h1buf[((p & 1) * BB + b) * HD + o + j], h1n,
                                   __ATOMIC_RELAXED, __HIP_MEMORY_SCOPE_AGENT);
                y[(size_t)(b * TT + (p - 1)) * HD + o + j] = h1n;
            }
        }
        __threadfence();
        __syncthreads();
        if (tid == 0) {
            __hip_atomic_store(myflag, (unsigned)(p + 1), __ATOMIC_RELEASE,
                               __HIP_MEMORY_SCOPE_AGENT);
        }
    }
}

// ---------------- Kernel C: logits = y @ Wd + bd ----------------
__global__ __launch_bounds__(256) void k_dense(
    const float* __restrict__ y, const float* __restrict__ Wd,
    const float* __restrict__ bd, float* __restrict__ out)
{
    __shared__ float ys[64 * HD];   // 32 KB
    const int r0 = blockIdx.x * 64;
    const int v0 = blockIdx.y * 128;
    const int tid = threadIdx.x;
    for (int idx = tid; idx < 64 * HD; idx += 256) ys[idx] = y[(size_t)r0 * HD + idx];
    __syncthreads();

    const int tx = tid & 31;      // 4 cols each -> 128 cols
    const int ty = tid >> 5;      // 8 rows each -> 64 rows
    const int v = v0 + tx * 4;
    float4 bd4 = *(const float4*)&bd[v];
    float acc[8][4] = {};
    const float* yrow = &ys[(ty * 8) * HD];
    #pragma unroll 4
    for (int e = 0; e < HD; ++e) {
        float4 w = *(const float4*)&Wd[(size_t)e * NV + v];
        #pragma unroll
        for (int j = 0; j < 8; ++j) {
            float yv = yrow[j * HD + e];
            acc[j][0] = fmaf(yv, w.x, acc[j][0]);
            acc[j][1] = fmaf(yv, w.y, acc[j][1]);
            acc[j][2] = fmaf(yv, w.z, acc[j][2]);
            acc[j][3] = fmaf(yv, w.w, acc[j][3]);
        }
    }
    #pragma unroll
    for (int j = 0; j < 8; ++j) {
        int rr = r0 + ty * 8 + j;
        float4 o4;
        o4.x = acc[j][0] + bd4.x;
        o4.y = acc[j][1] + bd4.y;
        o4.z = acc[j][2] + bd4.z;
        o4.w = acc[j][3] + bd4.w;
        *(float4*)&out[(size_t)rr * NV + v] = o4;
    }
}

extern "C" void kernel_launch(void* const* d_in, const int* in_sizes, int n_in,
                              void* d_out, int out_size, void* d_ws, size_t ws_size,
                              hipStream_t stream)
{
    const int*   inputs = (const int*)  d_in[0];
    const float* emb    = (const float*)d_in[1];
    const float* W0     = (const float*)d_in[2];
    const float* U0     = (const float*)d_in[3];
    const float* b0     = (const float*)d_in[4];
    const float* W1     = (const float*)d_in[5];
    const float* U1     = (const float*)d_in[6];
    const float* b1     = (const float*)d_in[7];
    const float* Wd     = (const float*)d_in[8];
    const float* bd     = (const float*)d_in[9];
    float* out = (float*)d_out;

    // Scratch: CTRL = flags(16KB) + h0buf(32KB) + h1buf(32KB) = 80KB,
    //          Z0x = 4096x512 f32 = 8MB, yy = 4096x128 f32 = 2MB.
    const size_t CTRL_BYTES = 80 * 1024;
    const size_t Z0X_BYTES  = (size_t)8 * 1024 * 1024;
    const size_t YY_BYTES   = (size_t)2 * 1024 * 1024;
    char* ws = (char*)d_ws;
    char* ctrl; float *Z0x, *yy;
    if (ws_size >= CTRL_BYTES + Z0X_BYTES + YY_BYTES + 4096) {
        ctrl = ws;
        Z0x  = (float*)(ws + CTRL_BYTES);
        yy   = (float*)(ws + CTRL_BYTES + Z0X_BYTES);
    } else {
        // ctrl + Z0x live in the tail of d_out (512MB): used only by
        // k_embed/k_lstm, which complete before k_dense rewrites all of out.
        size_t out_bytes = (size_t)out_size * sizeof(float);
        size_t tail = (out_bytes - (CTRL_BYTES + Z0X_BYTES)) & ~(size_t)1023;
        ctrl = (char*)d_out + tail;
        Z0x  = (float*)(ctrl + CTRL_BYTES);
        yy   = (float*)ws;   // 2MB — minimal ws requirement
    }
    unsigned int* flags = (unsigned int*)ctrl;
    float* h0buf = (float*)(ctrl + 16 * 1024);   // [2][BB][HD]
    float* h1buf = (float*)(ctrl + 48 * 1024);   // [2][BB][HD]

    // zero flags + h state each launch (graph replays re-run this)
    hipMemsetAsync(ctrl, 0, CTRL_BYTES, stream);

    k_embed_w0<<<512, 256, 0, stream>>>(inputs, emb, W0, b0, Z0x);

    k_lstm_d<<<256, 256, 0, stream>>>(Z0x, U0, W1, U1, b1, h0buf, h1buf, yy, flags);

    k_dense<<<dim3(64, 250), 256, 0, stream>>>(yy, Wd, bd, out);
}

// Round 4
// 2681.904 us; speedup vs baseline: 1.1810x; 1.1810x over previous
//
#include <hip/hip_runtime.h>
#include <math.h>

#define BB 32
#define TT 128
#define EE 128
#define HD 128
#define G4 512   // 4*H
#define NV 32000

// ---------------- Kernel A: Z0x = emb[inputs] @ W0 + b0 ----------------
__global__ __launch_bounds__(256) void k_embed_w0(
    const int* __restrict__ inputs, const float* __restrict__ emb,
    const float* __restrict__ W0, const float* __restrict__ b0,
    float* __restrict__ Z0x)
{
    __shared__ float xs[8][EE];
    const int r0 = blockIdx.x * 8;
    const int tid = threadIdx.x;
    for (int i = tid; i < 8 * EE; i += 256) {
        int r = i >> 7, e = i & 127;
        int tok = inputs[r0 + r];
        xs[r][e] = emb[tok * EE + e];
    }
    __syncthreads();
    const int c2 = tid * 2;
    float2 bb2 = *(const float2*)&b0[c2];
    float acc[8][2];
    #pragma unroll
    for (int r = 0; r < 8; ++r) { acc[r][0] = bb2.x; acc[r][1] = bb2.y; }
    for (int e = 0; e < EE; ++e) {
        float2 w = *(const float2*)&W0[e * G4 + c2];
        #pragma unroll
        for (int r = 0; r < 8; ++r) {
            float x = xs[r][e];
            acc[r][0] = fmaf(x, w.x, acc[r][0]);
            acc[r][1] = fmaf(x, w.y, acc[r][1]);
        }
    }
    #pragma unroll
    for (int r = 0; r < 8; ++r) {
        float2 o2; o2.x = acc[r][0]; o2.y = acc[r][1];
        *(float2*)&Z0x[(size_t)(r0 + r) * G4 + c2] = o2;
    }
}

// ---------------- Kernel B: 2-layer LSTM, one block per batch ----------------
// 32 blocks x 512 threads. Thread tid owns gate column tid (0..511) of each
// of the three recurrent matrices, ALL register-resident (384 VGPR).
// h0/h1/z in LDS. No inter-block communication.
// Phase A computes BOTH the U0 dot (h0_{t-1}) and the U1 dot (h1_{t-1}),
// so only the W1 dot sits on the critical path after layer-0 gates.
__global__ __launch_bounds__(512, 1) void k_lstm_r(
    const float* __restrict__ Z0x,
    const float* __restrict__ U0, const float* __restrict__ W1,
    const float* __restrict__ U1, const float* __restrict__ b1,
    float* __restrict__ y)
{
    const int b = blockIdx.x;
    const int tid = threadIdx.x;

    __shared__ float h0s[HD];
    __shared__ float h1s[HD];
    __shared__ float zb[G4];
    __shared__ float zu[G4];

    // register-resident weight columns for this thread's gate column
    float u0c[HD], w1c[HD], u1c[HD];
    #pragma unroll
    for (int e = 0; e < HD; ++e) u0c[e] = U0[e * G4 + tid];
    #pragma unroll
    for (int e = 0; e < HD; ++e) w1c[e] = W1[e * G4 + tid];
    #pragma unroll
    for (int e = 0; e < HD; ++e) u1c[e] = U1[e * G4 + tid];

    const float b1c = b1[tid];
    const float* __restrict__ zrow = Z0x + (size_t)b * TT * G4 + tid;

    float c0 = 0.f, c1 = 0.f;   // cell states (threads 0..127)
    if (tid < HD) { h0s[tid] = 0.f; h1s[tid] = 0.f; }
    __syncthreads();

    for (int t = 0; t < TT; ++t) {
        // ---- phase A: z0 = Z0x[b,t,:] + h0_{t-1}@U0 ; zu = h1_{t-1}@U1 ----
        float a0 = zrow[(size_t)t * G4];
        float au = 0.f;
        const float4* h04 = (const float4*)h0s;
        const float4* h14 = (const float4*)h1s;
        #pragma unroll
        for (int e4 = 0; e4 < 32; ++e4) {
            float4 h0v = h04[e4];
            float4 h1v = h14[e4];
            a0 = fmaf(h0v.x, u0c[4 * e4 + 0], a0);
            a0 = fmaf(h0v.y, u0c[4 * e4 + 1], a0);
            a0 = fmaf(h0v.z, u0c[4 * e4 + 2], a0);
            a0 = fmaf(h0v.w, u0c[4 * e4 + 3], a0);
            au = fmaf(h1v.x, u1c[4 * e4 + 0], au);
            au = fmaf(h1v.y, u1c[4 * e4 + 1], au);
            au = fmaf(h1v.z, u1c[4 * e4 + 2], au);
            au = fmaf(h1v.w, u1c[4 * e4 + 3], au);
        }
        zb[tid] = a0;
        zu[tid] = au;
        __syncthreads();

        // ---- phase B: layer-0 gates -> h0_t ----
        if (tid < HD) {
            float zi = zb[tid], zf = zb[HD + tid], zc = zb[2 * HD + tid], zo = zb[3 * HD + tid];
            float ig = 1.f / (1.f + expf(-zi));
            float fg = 1.f / (1.f + expf(-zf));
            float og = 1.f / (1.f + expf(-zo));
            c0 = fg * c0 + ig * tanhf(zc);
            h0s[tid] = og * tanhf(c0);
        }
        __syncthreads();

        // ---- phase C: z1 = b1 + zu + h0_t@W1 ----
        float a1 = b1c + zu[tid];
        #pragma unroll
        for (int e4 = 0; e4 < 32; ++e4) {
            float4 h0v = h04[e4];
            a1 = fmaf(h0v.x, w1c[4 * e4 + 0], a1);
            a1 = fmaf(h0v.y, w1c[4 * e4 + 1], a1);
            a1 = fmaf(h0v.z, w1c[4 * e4 + 2], a1);
            a1 = fmaf(h0v.w, w1c[4 * e4 + 3], a1);
        }
        zb[tid] = a1;
        __syncthreads();

        // ---- phase D: layer-1 gates -> h1_t, emit y ----
        if (tid < HD) {
            float zi = zb[tid], zf = zb[HD + tid], zc = zb[2 * HD + tid], zo = zb[3 * HD + tid];
            float ig = 1.f / (1.f + expf(-zi));
            float fg = 1.f / (1.f + expf(-zf));
            float og = 1.f / (1.f + expf(-zo));
            c1 = fg * c1 + ig * tanhf(zc);
            float hn = og * tanhf(c1);
            h1s[tid] = hn;
            y[(size_t)(b * TT + t) * HD + tid] = hn;
        }
        __syncthreads();
    }
}

// ---------------- Kernel C: logits = y @ Wd + bd ----------------
__global__ __launch_bounds__(256) void k_dense(
    const float* __restrict__ y, const float* __restrict__ Wd,
    const float* __restrict__ bd, float* __restrict__ out)
{
    __shared__ float ys[64 * HD];   // 32 KB
    const int r0 = blockIdx.x * 64;
    const int v0 = blockIdx.y * 128;
    const int tid = threadIdx.x;
    for (int idx = tid; idx < 64 * HD; idx += 256) ys[idx] = y[(size_t)r0 * HD + idx];
    __syncthreads();

    const int tx = tid & 31;      // 4 cols each -> 128 cols
    const int ty = tid >> 5;      // 8 rows each -> 64 rows
    const int v = v0 + tx * 4;
    float4 bd4 = *(const float4*)&bd[v];
    float acc[8][4] = {};
    const float* yrow = &ys[(ty * 8) * HD];
    #pragma unroll 4
    for (int e = 0; e < HD; ++e) {
        float4 w = *(const float4*)&Wd[(size_t)e * NV + v];
        #pragma unroll
        for (int j = 0; j < 8; ++j) {
            float yv = yrow[j * HD + e];
            acc[j][0] = fmaf(yv, w.x, acc[j][0]);
            acc[j][1] = fmaf(yv, w.y, acc[j][1]);
            acc[j][2] = fmaf(yv, w.z, acc[j][2]);
            acc[j][3] = fmaf(yv, w.w, acc[j][3]);
        }
    }
    #pragma unroll
    for (int j = 0; j < 8; ++j) {
        int rr = r0 + ty * 8 + j;
        float4 o4;
        o4.x = acc[j][0] + bd4.x;
        o4.y = acc[j][1] + bd4.y;
        o4.z = acc[j][2] + bd4.z;
        o4.w = acc[j][3] + bd4.w;
        *(float4*)&out[(size_t)rr * NV + v] = o4;
    }
}

extern "C" void kernel_launch(void* const* d_in, const int* in_sizes, int n_in,
                              void* d_out, int out_size, void* d_ws, size_t ws_size,
                              hipStream_t stream)
{
    const int*   inputs = (const int*)  d_in[0];
    const float* emb    = (const float*)d_in[1];
    const float* W0     = (const float*)d_in[2];
    const float* U0     = (const float*)d_in[3];
    const float* b0     = (const float*)d_in[4];
    const float* W1     = (const float*)d_in[5];
    const float* U1     = (const float*)d_in[6];
    const float* b1     = (const float*)d_in[7];
    const float* Wd     = (const float*)d_in[8];
    const float* bd     = (const float*)d_in[9];
    float* out = (float*)d_out;

    // scratch: Z0x = 4096x512 f32 = 8MB; yy = 4096x128 f32 = 2MB.
    const size_t Z0X_BYTES = (size_t)8 * 1024 * 1024;
    const size_t YY_BYTES  = (size_t)2 * 1024 * 1024;
    char* ws = (char*)d_ws;
    float *Z0x, *yy;
    if (ws_size >= Z0X_BYTES + YY_BYTES + 4096) {
        Z0x = (float*)ws;
        yy  = (float*)(ws + Z0X_BYTES);
    } else {
        // stage Z0x in the tail of d_out (read only by k_lstm_r, which
        // completes before k_dense rewrites all of d_out)
        size_t out_bytes = (size_t)out_size * sizeof(float);
        Z0x = (float*)((char*)d_out + out_bytes - Z0X_BYTES);
        yy  = (float*)ws;
    }

    k_embed_w0<<<512, 256, 0, stream>>>(inputs, emb, W0, b0, Z0x);

    k_lstm_r<<<BB, 512, 0, stream>>>(Z0x, U0, W1, U1, b1, yy);

    k_dense<<<dim3(64, 250), 256, 0, stream>>>(yy, Wd, bd, out);
}

// Round 5
// 883.054 us; speedup vs baseline: 3.5868x; 3.0371x over previous
//
#include <hip/hip_runtime.h>
#include <math.h>

#define BB 32
#define TT 128
#define EE 128
#define HD 128
#define G4 512   // 4*H
#define NV 32000

typedef _Float16 f16x2 __attribute__((ext_vector_type(2)));

// ---------------- Kernel A: Z0x = emb[inputs] @ W0 + b0 ----------------
__global__ __launch_bounds__(256) void k_embed_w0(
    const int* __restrict__ inputs, const float* __restrict__ emb,
    const float* __restrict__ W0, const float* __restrict__ b0,
    float* __restrict__ Z0x)
{
    __shared__ float xs[8][EE];
    const int r0 = blockIdx.x * 8;
    const int tid = threadIdx.x;
    for (int i = tid; i < 8 * EE; i += 256) {
        int r = i >> 7, e = i & 127;
        int tok = inputs[r0 + r];
        xs[r][e] = emb[tok * EE + e];
    }
    __syncthreads();
    const int c2 = tid * 2;
    float2 bb2 = *(const float2*)&b0[c2];
    float acc[8][2];
    #pragma unroll
    for (int r = 0; r < 8; ++r) { acc[r][0] = bb2.x; acc[r][1] = bb2.y; }
    for (int e = 0; e < EE; ++e) {
        float2 w = *(const float2*)&W0[e * G4 + c2];
        #pragma unroll
        for (int r = 0; r < 8; ++r) {
            float x = xs[r][e];
            acc[r][0] = fmaf(x, w.x, acc[r][0]);
            acc[r][1] = fmaf(x, w.y, acc[r][1]);
        }
    }
    #pragma unroll
    for (int r = 0; r < 8; ++r) {
        float2 o2; o2.x = acc[r][0]; o2.y = acc[r][1];
        *(float2*)&Z0x[(size_t)(r0 + r) * G4 + c2] = o2;
    }
}

// ---------------- Kernel B: 2-layer LSTM, one block per batch ----------------
// 32 blocks x 512 threads, launch_bounds(512,2) -> 256 VGPR budget.
// Thread tid owns gate column tid of U0, W1, U1, stored as 3x64 packed f16x2
// (192 VGPR) — f16 weights, exact-product f32 accumulation via v_dot2_f32_f16.
// h passes through LDS as f16; gates/cell state fp32. No cross-block comm.
__global__ __launch_bounds__(512, 2) void k_lstm_f(
    const float* __restrict__ Z0x,
    const float* __restrict__ U0, const float* __restrict__ W1,
    const float* __restrict__ U1, const float* __restrict__ b1,
    float* __restrict__ y)
{
    const int b = blockIdx.x;
    const int tid = threadIdx.x;

    __shared__ _Float16 h0p[HD];   // packed h0_{t-1} (f16)
    __shared__ _Float16 h1p[HD];   // packed h1_{t-1} (f16)
    __shared__ float zb[G4];
    __shared__ float zu[G4];

    // register-resident f16 weight columns (192 VGPR)
    f16x2 u0c[64], w1c[64], u1c[64];
    #pragma unroll
    for (int e2 = 0; e2 < 64; ++e2) {
        u0c[e2] = f16x2{(_Float16)U0[(2 * e2) * G4 + tid], (_Float16)U0[(2 * e2 + 1) * G4 + tid]};
        w1c[e2] = f16x2{(_Float16)W1[(2 * e2) * G4 + tid], (_Float16)W1[(2 * e2 + 1) * G4 + tid]};
        u1c[e2] = f16x2{(_Float16)U1[(2 * e2) * G4 + tid], (_Float16)U1[(2 * e2 + 1) * G4 + tid]};
    }

    const float b1c = b1[tid];
    const float* __restrict__ zrow = Z0x + (size_t)b * TT * G4 + tid;

    float c0 = 0.f, c1 = 0.f;   // cell states (threads 0..127)
    if (tid < HD) { h0p[tid] = (_Float16)0.f; h1p[tid] = (_Float16)0.f; }
    __syncthreads();

    const f16x2* h0v = (const f16x2*)h0p;
    const f16x2* h1v = (const f16x2*)h1p;

    for (int t = 0; t < TT; ++t) {
        // ---- phase A: z0 = Z0x[b,t] + h0@U0 ; zu = h1@U1 ----
        float a0a = zrow[(size_t)t * G4], a0b = 0.f;
        float aua = 0.f, aub = 0.f;
        #pragma unroll
        for (int e2 = 0; e2 < 64; e2 += 2) {
            a0a = __builtin_amdgcn_fdot2(h0v[e2],     u0c[e2],     a0a, false);
            a0b = __builtin_amdgcn_fdot2(h0v[e2 + 1], u0c[e2 + 1], a0b, false);
            aua = __builtin_amdgcn_fdot2(h1v[e2],     u1c[e2],     aua, false);
            aub = __builtin_amdgcn_fdot2(h1v[e2 + 1], u1c[e2 + 1], aub, false);
        }
        zb[tid] = a0a + a0b;
        zu[tid] = aua + aub;
        __syncthreads();

        // ---- phase B: layer-0 gates -> h0_t (f16 to LDS) ----
        if (tid < HD) {
            float zi = zb[tid], zf = zb[HD + tid], zc = zb[2 * HD + tid], zo = zb[3 * HD + tid];
            float ig = 1.f / (1.f + expf(-zi));
            float fg = 1.f / (1.f + expf(-zf));
            float og = 1.f / (1.f + expf(-zo));
            c0 = fg * c0 + ig * tanhf(zc);
            h0p[tid] = (_Float16)(og * tanhf(c0));
        }
        __syncthreads();

        // ---- phase C: z1 = b1 + zu + h0_t@W1 ----
        float a1a = b1c + zu[tid], a1b = 0.f;
        #pragma unroll
        for (int e2 = 0; e2 < 64; e2 += 2) {
            a1a = __builtin_amdgcn_fdot2(h0v[e2],     w1c[e2],     a1a, false);
            a1b = __builtin_amdgcn_fdot2(h0v[e2 + 1], w1c[e2 + 1], a1b, false);
        }
        zb[tid] = a1a + a1b;
        __syncthreads();

        // ---- phase D: layer-1 gates -> h1_t (f16 to LDS), y (f32) ----
        if (tid < HD) {
            float zi = zb[tid], zf = zb[HD + tid], zc = zb[2 * HD + tid], zo = zb[3 * HD + tid];
            float ig = 1.f / (1.f + expf(-zi));
            float fg = 1.f / (1.f + expf(-zf));
            float og = 1.f / (1.f + expf(-zo));
            c1 = fg * c1 + ig * tanhf(zc);
            float hn = og * tanhf(c1);
            h1p[tid] = (_Float16)hn;
            y[(size_t)(b * TT + t) * HD + tid] = hn;
        }
        __syncthreads();
    }
}

// ---------------- Kernel C: logits = y @ Wd + bd ----------------
__global__ __launch_bounds__(256) void k_dense(
    const float* __restrict__ y, const float* __restrict__ Wd,
    const float* __restrict__ bd, float* __restrict__ out)
{
    __shared__ float ys[64 * HD];   // 32 KB
    const int r0 = blockIdx.x * 64;
    const int v0 = blockIdx.y * 128;
    const int tid = threadIdx.x;
    for (int idx = tid; idx < 64 * HD; idx += 256) ys[idx] = y[(size_t)r0 * HD + idx];
    __syncthreads();

    const int tx = tid & 31;      // 4 cols each -> 128 cols
    const int ty = tid >> 5;      // 8 rows each -> 64 rows
    const int v = v0 + tx * 4;
    float4 bd4 = *(const float4*)&bd[v];
    float acc[8][4] = {};
    const float* yrow = &ys[(ty * 8) * HD];
    #pragma unroll 4
    for (int e = 0; e < HD; ++e) {
        float4 w = *(const float4*)&Wd[(size_t)e * NV + v];
        #pragma unroll
        for (int j = 0; j < 8; ++j) {
            float yv = yrow[j * HD + e];
            acc[j][0] = fmaf(yv, w.x, acc[j][0]);
            acc[j][1] = fmaf(yv, w.y, acc[j][1]);
            acc[j][2] = fmaf(yv, w.z, acc[j][2]);
            acc[j][3] = fmaf(yv, w.w, acc[j][3]);
        }
    }
    #pragma unroll
    for (int j = 0; j < 8; ++j) {
        int rr = r0 + ty * 8 + j;
        float4 o4;
        o4.x = acc[j][0] + bd4.x;
        o4.y = acc[j][1] + bd4.y;
        o4.z = acc[j][2] + bd4.z;
        o4.w = acc[j][3] + bd4.w;
        *(float4*)&out[(size_t)rr * NV + v] = o4;
    }
}

extern "C" void kernel_launch(void* const* d_in, const int* in_sizes, int n_in,
                              void* d_out, int out_size, void* d_ws, size_t ws_size,
                              hipStream_t stream)
{
    const int*   inputs = (const int*)  d_in[0];
    const float* emb    = (const float*)d_in[1];
    const float* W0     = (const float*)d_in[2];
    const float* U0     = (const float*)d_in[3];
    const float* b0     = (const float*)d_in[4];
    const float* W1     = (const float*)d_in[5];
    const float* U1     = (const float*)d_in[6];
    const float* b1     = (const float*)d_in[7];
    const float* Wd     = (const float*)d_in[8];
    const float* bd     = (const float*)d_in[9];
    float* out = (float*)d_out;

    // scratch: Z0x = 4096x512 f32 = 8MB; yy = 4096x128 f32 = 2MB.
    const size_t Z0X_BYTES = (size_t)8 * 1024 * 1024;
    const size_t YY_BYTES  = (size_t)2 * 1024 * 1024;
    char* ws = (char*)d_ws;
    float *Z0x, *yy;
    if (ws_size >= Z0X_BYTES + YY_BYTES + 4096) {
        Z0x = (float*)ws;
        yy  = (float*)(ws + Z0X_BYTES);
    } else {
        // stage Z0x in the tail of d_out (read only by k_lstm_f, which
        // completes before k_dense rewrites all of d_out)
        size_t out_bytes = (size_t)out_size * sizeof(float);
        Z0x = (float*)((char*)d_out + out_bytes - Z0X_BYTES);
        yy  = (float*)ws;
    }

    k_embed_w0<<<512, 256, 0, stream>>>(inputs, emb, W0, b0, Z0x);

    k_lstm_f<<<BB, 512, 0, stream>>>(Z0x, U0, W1, U1, b1, yy);

    k_dense<<<dim3(64, 250), 256, 0, stream>>>(yy, Wd, bd, out);
}